// Round 1
// baseline (9419.884 us; speedup 1.0000x reference)
//
#include <hip/hip_runtime.h>
#include <math.h>

// Problem constants
namespace {
constexpr int Bb = 2, Nn = 1024, Dd = 256, Hh = 8, DHh = 32, II = 1024, Vv = 32000;
constexpr int ROWS = Bb * Nn;           // 2048
constexpr int BH = Bb * Hh;             // 16
constexpr size_t LOGITS_PER = (size_t)Bb * Nn * Vv;   // 65,536,000
constexpr size_t LOGITS_TOT = 4 * LOGITS_PER;         // 262,144,000
}

// ---------------- block reduction helper (256 threads) ----------------
__device__ __forceinline__ float block_sum256(float v, float* red) {
    int d = threadIdx.x;
    red[d] = v; __syncthreads();
    #pragma unroll
    for (int s = 128; s > 0; s >>= 1) {
        if (d < s) red[d] += red[d + s];
        __syncthreads();
    }
    float r = red[0]; __syncthreads();
    return r;
}

// ---------------- embedding + input LayerNorm -> X, Q ----------------
__global__ __launch_bounds__(256) void embed_ln_k(
    const int* __restrict__ ids, const float* __restrict__ emb,
    const float* __restrict__ pos, const float* __restrict__ w,
    const float* __restrict__ bias, float* __restrict__ X, float* __restrict__ Q)
{
    __shared__ float red[256];
    int r = blockIdx.x, d = threadIdx.x;
    int n = r & (Nn - 1);
    int id = ids[r];
    float x = emb[(size_t)id * Dd + d] + pos[(size_t)n * Dd + d];
    float mu = block_sum256(x, red) * (1.f / Dd);
    float xc = x - mu;
    float var = block_sum256(xc * xc, red) * (1.f / Dd);
    float y = xc * rsqrtf(var + 1e-5f) * w[d] + bias[d];
    X[(size_t)r * Dd + d] = y;
    Q[(size_t)r * Dd + d] = y;
}

// ---------------- generic LayerNorm (optional +add) ----------------
__global__ __launch_bounds__(256) void ln_k(
    const float* __restrict__ in, const float* __restrict__ add,
    const float* __restrict__ w, const float* __restrict__ bias,
    float* __restrict__ out)
{
    __shared__ float red[256];
    int r = blockIdx.x, d = threadIdx.x;
    float x = in[(size_t)r * Dd + d];
    float mu = block_sum256(x, red) * (1.f / Dd);
    float xc = x - mu;
    float var = block_sum256(xc * xc, red) * (1.f / Dd);
    float y = xc * rsqrtf(var + 1e-5f) * w[d] + bias[d];
    if (add) y += add[(size_t)r * Dd + d];
    out[(size_t)r * Dd + d] = y;
}

// ---------------- 64x64 f32 GEMM core (K % 16 == 0, no bounds) ----------------
__device__ __forceinline__ void gemm_core(
    const float* __restrict__ A, const float* __restrict__ Bm,
    int Kdim, int ldb, int m0, int n0,
    float (&acc)[4][4], float (&As)[16][64], float (&Bs)[16][64])
{
    int tid = threadIdx.x;
    int tx = tid & 15, ty = tid >> 4;
    int arow = tid >> 2, ak = (tid & 3) << 2;
    for (int k0 = 0; k0 < Kdim; k0 += 16) {
        float4 av = *(const float4*)(A + (size_t)(m0 + arow) * Kdim + k0 + ak);
        As[ak + 0][arow] = av.x; As[ak + 1][arow] = av.y;
        As[ak + 2][arow] = av.z; As[ak + 3][arow] = av.w;
        *(float4*)(&Bs[ty][tx << 2]) =
            *(const float4*)(Bm + (size_t)(k0 + ty) * ldb + n0 + (tx << 2));
        __syncthreads();
        #pragma unroll
        for (int kk = 0; kk < 16; ++kk) {
            float a[4], bv[4];
            #pragma unroll
            for (int i = 0; i < 4; ++i) a[i] = As[kk][(ty << 2) + i];
            #pragma unroll
            for (int j = 0; j < 4; ++j) bv[j] = Bs[kk][(tx << 2) + j];
            #pragma unroll
            for (int i = 0; i < 4; ++i)
                #pragma unroll
                for (int j = 0; j < 4; ++j)
                    acc[i][j] = fmaf(a[i], bv[j], acc[i][j]);
        }
        __syncthreads();
    }
}

// ---------------- QKV projection (z = 0:q, 1:k, 2:v), writes (B,H,N,DH) ----------------
__global__ __launch_bounds__(256) void gemm_qkv_k(
    const float* __restrict__ Hc, const float* __restrict__ Wq,
    const float* __restrict__ Wk, const float* __restrict__ Wv,
    float* __restrict__ pq, float* __restrict__ pk, float* __restrict__ pv, int kblk)
{
    __shared__ float As[16][64], Bs[16][64];
    float acc[4][4] = {};
    int z = blockIdx.z;
    const float* Wsel = (z == 0 ? Wq : (z == 1 ? Wk : Wv)) + (size_t)kblk * Dd * Dd;
    int m0 = blockIdx.x * 64, n0 = blockIdx.y * 64;
    gemm_core(Hc, Wsel, Dd, Dd, m0, n0, acc, As, Bs);
    float* dst = (z == 0 ? pq : (z == 1 ? pk : pv));
    int tx = threadIdx.x & 15, ty = threadIdx.x >> 4;
    #pragma unroll
    for (int i = 0; i < 4; ++i) {
        int r = m0 + (ty << 2) + i;
        int b = r >> 10, n = r & 1023;
        #pragma unroll
        for (int j = 0; j < 4; ++j) {
            int c = n0 + (tx << 2) + j;
            int h = c >> 5, dh = c & 31;
            float v = acc[i][j];
            if (z < 2) v = (v > 0.f) ? v + 1.f : expf(v);   // elu(x)+1
            dst[((size_t)(b * Hh + h) * Nn + n) * DHh + dh] = v;
        }
    }
}

// ---------------- attention pass 1: partial num/den over an m-chunk ----------------
__global__ __launch_bounds__(256) void attn1_k(
    const float* __restrict__ pq, const float* __restrict__ pk,
    const float* __restrict__ pv, float* __restrict__ pnum, float* __restrict__ pden)
{
    __shared__ float pk_s[64][32];
    __shared__ float v_s[64][32];
    int tid = threadIdx.x;
    int n = blockIdx.x * 256 + tid;    // query row within (b,h)
    int bh = blockIdx.y;
    int ms = blockIdx.z;               // m-split 0..3 (256 keys each)
    const float* qrow = pq + ((size_t)bh * Nn + n) * DHh;
    float pqr[32];
    #pragma unroll
    for (int d = 0; d < 32; d += 4) {
        float4 t = *(const float4*)(qrow + d);
        pqr[d] = t.x; pqr[d + 1] = t.y; pqr[d + 2] = t.z; pqr[d + 3] = t.w;
    }
    float acc[32];
    #pragma unroll
    for (int d = 0; d < 32; ++d) acc[d] = 0.f;
    float den = 0.f;
    for (int ch = 0; ch < 4; ++ch) {
        int mb = ms * 256 + ch * 64;
        const float4* ksrc = (const float4*)(pk + ((size_t)bh * Nn + mb) * DHh);
        const float4* vsrc = (const float4*)(pv + ((size_t)bh * Nn + mb) * DHh);
        float4* kd = (float4*)pk_s;
        float4* vd = (float4*)v_s;
        kd[tid] = ksrc[tid]; kd[tid + 256] = ksrc[tid + 256];
        vd[tid] = vsrc[tid]; vd[tid + 256] = vsrc[tid + 256];
        __syncthreads();
        #pragma unroll 4
        for (int mm = 0; mm < 64; ++mm) {
            float w0 = 0.f, w1 = 0.f, w2 = 0.f, w3 = 0.f;
            #pragma unroll
            for (int d = 0; d < 32; d += 4) {
                w0 = fmaf(pqr[d + 0], pk_s[mm][d + 0], w0);
                w1 = fmaf(pqr[d + 1], pk_s[mm][d + 1], w1);
                w2 = fmaf(pqr[d + 2], pk_s[mm][d + 2], w2);
                w3 = fmaf(pqr[d + 3], pk_s[mm][d + 3], w3);
            }
            float w = (w0 + w1) + (w2 + w3);
            w = fmaxf(w, 0.f);
            w = w * w;                 // relu(W)^2
            den += w;
            #pragma unroll
            for (int d = 0; d < 32; ++d) acc[d] = fmaf(w, v_s[mm][d], acc[d]);
        }
        __syncthreads();
    }
    float* np_ = pnum + ((size_t)(ms * BH + bh) * Nn + n) * DHh;
    #pragma unroll
    for (int d = 0; d < 32; d += 4) {
        float4 t; t.x = acc[d]; t.y = acc[d + 1]; t.z = acc[d + 2]; t.w = acc[d + 3];
        *(float4*)(np_ + d) = t;
    }
    pden[(size_t)(ms * BH + bh) * Nn + n] = den;
}

// ---------------- attention pass 2: combine splits, m = C - v, to (B,N,D) ----------------
__global__ __launch_bounds__(256) void attn2_k(
    const float* __restrict__ pnum, const float* __restrict__ pden,
    const float* __restrict__ pv, float* __restrict__ mout)
{
    int e = blockIdx.x * 256 + threadIdx.x;    // < 16*1024*32 = 524288
    int bhn = e >> 5, d = e & 31;
    float num = 0.f, den = 0.f;
    #pragma unroll
    for (int ms = 0; ms < 4; ++ms) {
        num += pnum[(size_t)ms * (BH * Nn * DHh) + e];
        den += pden[(size_t)ms * (BH * Nn) + bhn];
    }
    float C = num / (den + 1.f);
    float mv = C - pv[e];
    int n = bhn & 1023, bh = bhn >> 10;
    int b = bh >> 3, h = bh & 7;
    mout[((size_t)(b * Nn) + n) * Dd + h * DHh + d] = mv;
}

// ---------------- Wo GEMM: Qi = Q + softplus(dt) * (m @ Wo) ----------------
__global__ __launch_bounds__(256) void gemm_wo_k(
    const float* __restrict__ Am, const float* __restrict__ Wo,
    const float* __restrict__ Qsrc, const float* __restrict__ dts,
    float* __restrict__ Qi, int kblk)
{
    __shared__ float As[16][64], Bs[16][64];
    float acc[4][4] = {};
    const float* Bm = Wo + (size_t)kblk * Dd * Dd;
    int m0 = blockIdx.x * 64, n0 = blockIdx.y * 64;
    gemm_core(Am, Bm, Dd, Dd, m0, n0, acc, As, Bs);
    float spdt = log1pf(expf(dts[kblk]));
    int tx = threadIdx.x & 15, ty = threadIdx.x >> 4;
    #pragma unroll
    for (int i = 0; i < 4; ++i) {
        int r = m0 + (ty << 2) + i;
        #pragma unroll
        for (int j = 0; j < 4; ++j) {
            int c = n0 + (tx << 2) + j;
            size_t o = (size_t)r * Dd + c;
            Qi[o] = Qsrc[o] + spdt * acc[i][j];
        }
    }
}

// ---------------- Up GEMM (dual-column): Hf = silu(G) * U ----------------
__global__ __launch_bounds__(256) void gemm_up_k(
    const float* __restrict__ A, const float* __restrict__ Wup,
    float* __restrict__ Hf, int kblk)
{
    __shared__ float As[16][64], Bg[16][64], Bu[16][64];
    float accg[4][4] = {}, accu[4][4] = {};
    const float* Bm = Wup + (size_t)kblk * (Dd * 2 * II);
    int tid = threadIdx.x, tx = tid & 15, ty = tid >> 4;
    int m0 = blockIdx.x * 64, n0 = blockIdx.y * 64;
    int arow = tid >> 2, ak = (tid & 3) << 2;
    for (int k0 = 0; k0 < Dd; k0 += 16) {
        float4 av = *(const float4*)(A + (size_t)(m0 + arow) * Dd + k0 + ak);
        As[ak + 0][arow] = av.x; As[ak + 1][arow] = av.y;
        As[ak + 2][arow] = av.z; As[ak + 3][arow] = av.w;
        const float* bp = Bm + (size_t)(k0 + ty) * (2 * II);
        *(float4*)(&Bg[ty][tx << 2]) = *(const float4*)(bp + n0 + (tx << 2));
        *(float4*)(&Bu[ty][tx << 2]) = *(const float4*)(bp + II + n0 + (tx << 2));
        __syncthreads();
        #pragma unroll
        for (int kk = 0; kk < 16; ++kk) {
            float a[4], g[4], u[4];
            #pragma unroll
            for (int i = 0; i < 4; ++i) a[i] = As[kk][(ty << 2) + i];
            #pragma unroll
            for (int j = 0; j < 4; ++j) { g[j] = Bg[kk][(tx << 2) + j]; u[j] = Bu[kk][(tx << 2) + j]; }
            #pragma unroll
            for (int i = 0; i < 4; ++i)
                #pragma unroll
                for (int j = 0; j < 4; ++j) {
                    accg[i][j] = fmaf(a[i], g[j], accg[i][j]);
                    accu[i][j] = fmaf(a[i], u[j], accu[i][j]);
                }
        }
        __syncthreads();
    }
    #pragma unroll
    for (int i = 0; i < 4; ++i) {
        int r = m0 + (ty << 2) + i;
        #pragma unroll
        for (int j = 0; j < 4; ++j) {
            int c = n0 + (tx << 2) + j;
            float g = accg[i][j], u = accu[i][j];
            float hf = g / (1.f + expf(-g)) * u;   // silu(g)*u
            Hf[(size_t)r * II + c] = hf;
        }
    }
}

// ---------------- depthwise conv1d over n (kernel 3, pad 1) ----------------
__global__ __launch_bounds__(256) void conv_k(
    const float* __restrict__ Hf, const float* __restrict__ cw,
    float* __restrict__ Hc2, int kblk)
{
    int e = blockIdx.x * 256 + threadIdx.x;   // < 2048*1024
    int c = e & 1023, r = e >> 10;
    int n = r & 1023;
    const float* wp = cw + ((size_t)kblk * II + c) * 3;
    float w0 = wp[0], w1 = wp[1], w2 = wp[2];
    float h1 = Hf[e];
    float h0 = (n > 0)    ? Hf[e - II] : 0.f;
    float h2 = (n < 1023) ? Hf[e + II] : 0.f;
    Hc2[e] = h0 * w0 + h1 * w1 + h2 * w2;
}

// ---------------- Wd GEMM: Qnew = Qi + Hc2 @ Wd ----------------
__global__ __launch_bounds__(256) void gemm_wd_k(
    const float* __restrict__ A, const float* __restrict__ Wd,
    const float* __restrict__ Qi, float* __restrict__ Qout, int kblk)
{
    __shared__ float As[16][64], Bs[16][64];
    float acc[4][4] = {};
    const float* Bm = Wd + (size_t)kblk * II * Dd;
    int m0 = blockIdx.x * 64, n0 = blockIdx.y * 64;
    gemm_core(A, Bm, II, Dd, m0, n0, acc, As, Bs);
    int tx = threadIdx.x & 15, ty = threadIdx.x >> 4;
    #pragma unroll
    for (int i = 0; i < 4; ++i) {
        int r = m0 + (ty << 2) + i;
        #pragma unroll
        for (int j = 0; j < 4; ++j) {
            int c = n0 + (tx << 2) + j;
            size_t o = (size_t)r * Dd + c;
            Qout[o] = Qi[o] + acc[i][j];
        }
    }
}

// ---------------- LM head GEMM: out = Qn @ lm_w ----------------
__global__ __launch_bounds__(256) void gemm_lm_k(
    const float* __restrict__ Qn, const float* __restrict__ lm,
    float* __restrict__ out)
{
    __shared__ float As[16][64], Bs[16][64];
    float acc[4][4] = {};
    int m0 = blockIdx.x * 64, n0 = blockIdx.y * 64;
    gemm_core(Qn, lm, Dd, Vv, m0, n0, acc, As, Bs);
    int tx = threadIdx.x & 15, ty = threadIdx.x >> 4;
    #pragma unroll
    for (int i = 0; i < 4; ++i) {
        int r = m0 + (ty << 2) + i;
        #pragma unroll
        for (int j = 0; j < 4; ++j) {
            int c = n0 + (tx << 2) + j;
            out[(size_t)r * Vv + c] = acc[i][j];
        }
    }
}

// ---------------- halt head: sigmoid(mean_n(Qn) @ halt_w + halt_b) ----------------
__global__ __launch_bounds__(256) void halt_k(
    const float* __restrict__ Qn, const float* __restrict__ hw,
    const float* __restrict__ hb, float* __restrict__ out, int lp)
{
    __shared__ float red[256];
    int b = blockIdx.x, d = threadIdx.x;
    float s = 0.f;
    for (int n = 0; n < Nn; ++n) s += Qn[((size_t)b * Nn + n) * Dd + d];
    float mean = s * (1.f / Nn);
    float val = block_sum256(mean * hw[d], red);
    if (d == 0) {
        float x = val + hb[0];
        out[LOGITS_TOT + (size_t)lp * Bb + b] = 1.f / (1.f + expf(-x));
    }
}

// ---------------- host launch ----------------
extern "C" void kernel_launch(void* const* d_in, const int* in_sizes, int n_in,
                              void* d_out, int out_size, void* d_ws, size_t ws_size,
                              hipStream_t stream) {
    (void)in_sizes; (void)n_in; (void)out_size; (void)ws_size;
    const int*   ids   = (const int*)d_in[0];
    const float* emb   = (const float*)d_in[1];
    const float* pos   = (const float*)d_in[2];
    const float* in_w  = (const float*)d_in[3];
    const float* in_b  = (const float*)d_in[4];
    const float* Wq    = (const float*)d_in[5];
    const float* Wk    = (const float*)d_in[6];
    const float* Wv    = (const float*)d_in[7];
    const float* Wo    = (const float*)d_in[8];
    const float* dts   = (const float*)d_in[9];
    const float* Wup   = (const float*)d_in[10];
    const float* cw    = (const float*)d_in[11];
    const float* Wd    = (const float*)d_in[12];
    const float* n1w   = (const float*)d_in[13];
    const float* n1b   = (const float*)d_in[14];
    const float* n2w   = (const float*)d_in[15];
    const float* n2b   = (const float*)d_in[16];
    const float* fin_w = (const float*)d_in[17];
    const float* fin_b = (const float*)d_in[18];
    const float* hw    = (const float*)d_in[19];
    const float* hb    = (const float*)d_in[20];
    const float* lm    = (const float*)d_in[21];
    float* out = (float*)d_out;

    // workspace layout (floats)
    float* ws   = (float*)d_ws;
    float* X    = ws;                         // 524288
    float* Q    = X    + 524288;              // 524288
    float* tmpA = Q    + 524288;              // Hc / Y / Qn
    float* pqm  = tmpA + 524288;              // pq, later m
    float* pkqi = pqm  + 524288;              // pk, later Qi
    float* pv   = pkqi + 524288;              // v
    float* Hf   = pv   + 524288;              // 2097152
    float* Hc2  = Hf   + 2097152;             // 2097152
    float* pnum = Hc2  + 2097152;             // 2097152
    float* pden = pnum + 2097152;             // 65536

    embed_ln_k<<<ROWS, 256, 0, stream>>>(ids, emb, pos, in_w, in_b, X, Q);

    for (int l = 0; l < 8; ++l) {
        for (int k = 0; k < 4; ++k) {
            // Hc = LN(Q; n1) + X
            ln_k<<<ROWS, 256, 0, stream>>>(Q, X, n1w + k * Dd, n1b + k * Dd, tmpA);
            // q,k,v projections (+ elu+1 on q,k), layout (B,H,N,DH)
            gemm_qkv_k<<<dim3(32, 4, 3), 256, 0, stream>>>(tmpA, Wq, Wk, Wv, pqm, pkqi, pv, k);
            // linear attention with relu^2 kernel, split over m
            attn1_k<<<dim3(4, 16, 4), 256, 0, stream>>>(pqm, pkqi, pv, pnum, pden);
            attn2_k<<<2048, 256, 0, stream>>>(pnum, pden, pv, pqm);       // m into pq buffer
            // Qi = Q + softplus(dt) * (m @ Wo)
            gemm_wo_k<<<dim3(32, 4), 256, 0, stream>>>(pqm, Wo, Q, dts, pkqi, k); // Qi into pk buffer
            // Y = LN(Qi; n2)
            ln_k<<<ROWS, 256, 0, stream>>>(pkqi, nullptr, n2w + k * Dd, n2b + k * Dd, tmpA);
            // Hf = silu(G)*U
            gemm_up_k<<<dim3(32, 16), 256, 0, stream>>>(tmpA, Wup, Hf, k);
            // depthwise conv over n
            conv_k<<<8192, 256, 0, stream>>>(Hf, cw, Hc2, k);
            // Q = Qi + Hc2 @ Wd
            gemm_wd_k<<<dim3(32, 4), 256, 0, stream>>>(Hc2, Wd, pkqi, Q, k);
        }
        if (l >= 4) {
            int lp = l - 4;
            ln_k<<<ROWS, 256, 0, stream>>>(Q, nullptr, fin_w, fin_b, tmpA);
            halt_k<<<Bb, 256, 0, stream>>>(tmpA, hw, hb, out, lp);
            gemm_lm_k<<<dim3(32, 500), 256, 0, stream>>>(tmpA, lm, out + (size_t)lp * LOGITS_PER);
        }
    }
}